// Round 1
// baseline (490.323 us; speedup 1.0000x reference)
//
#include <hip/hip_runtime.h>
#include <stdint.h>

#define AS1 __attribute__((address_space(1)))
#define AS3 __attribute__((address_space(3)))

using bf16x8_t = __attribute__((ext_vector_type(8))) __bf16;
using f32x4_t  = __attribute__((ext_vector_type(4))) float;

__device__ __forceinline__ uint16_t f2bf(float f) {
    union { float f; uint32_t u; } v; v.f = f;
    return (uint16_t)((v.u + 0x7fffu + ((v.u >> 16) & 1u)) >> 16);
}
__device__ __forceinline__ float bf2f(uint16_t h) {
    union { uint32_t u; float f; } v; v.u = ((uint32_t)h) << 16;
    return v.f;
}

// ---- k0: x1 f32 -> bf16 ----
__global__ __launch_bounds__(256) void k_convert(const float* __restrict__ x,
                                                 uint16_t* __restrict__ o, int n4) {
    int i = blockIdx.x * 256 + threadIdx.x;
    int stride = gridDim.x * 256;
    for (; i < n4; i += stride) {
        float4 v = ((const float4*)x)[i];
        ushort4 u;
        u.x = f2bf(v.x); u.y = f2bf(v.y); u.z = f2bf(v.z); u.w = f2bf(v.w);
        ((ushort4*)o)[i] = u;
    }
}

// ---- k1: colsum[b][ch] = sum_n exp(x2[b,n,ch]) ----
__global__ __launch_bounds__(256) void k_colsum(const float* __restrict__ x2,
                                                float* __restrict__ colsum) {
    int bx = blockIdx.x;                 // cg + 4*(b + 4*ns)
    int cg = bx & 3, b = (bx >> 2) & 3, ns = bx >> 4;
    int ch = cg * 256 + threadIdx.x;
    const float* p = x2 + ((size_t)b * 4096 + (size_t)ns * 256) * 1024 + ch;
    float s = 0.f;
    for (int n = 0; n < 256; ++n) { s += __expf(*p); p += 1024; }
    atomicAdd(&colsum[b * 1024 + ch], s);
}

// ---- k2: partial S[b,h,i,j] = sum_n (E[n,i]/qden[n]) * E[n,j], E = exp(x2 head slice) ----
__global__ __launch_bounds__(256) void k_spart(const float* __restrict__ x2,
                                               float* __restrict__ spart) {
    int bx = blockIdx.x;                 // bh + 32*ns
    int bh = bx & 31, ns = bx >> 5;
    int b = bh >> 3, h = bh & 7;
    __shared__ float e[16 * 128];
    __shared__ float qd[16];
    int t = threadIdx.x;
    int r = t >> 4;                      // 0..15 : load-row, also i-tile
    int g = t & 15;                      // 0..15 : col-group, also j-tile
    float acc[8][8] = {};
    const float* base = x2 + ((size_t)b * 4096 + (size_t)ns * 512) * 1024 + h * 128;
    for (int it = 0; it < 32; ++it) {
        const float* rp = base + (size_t)(it * 16 + r) * 1024 + g * 8;
        float4 v0 = ((const float4*)rp)[0];
        float4 v1 = ((const float4*)rp)[1];
        float ev[8];
        ev[0] = __expf(v0.x); ev[1] = __expf(v0.y); ev[2] = __expf(v0.z); ev[3] = __expf(v0.w);
        ev[4] = __expf(v1.x); ev[5] = __expf(v1.y); ev[6] = __expf(v1.z); ev[7] = __expf(v1.w);
        float ps = ((ev[0]+ev[1])+(ev[2]+ev[3])) + ((ev[4]+ev[5])+(ev[6]+ev[7]));
        float* ep = &e[r * 128 + g * 8];
        ((float4*)ep)[0] = make_float4(ev[0], ev[1], ev[2], ev[3]);
        ((float4*)ep)[1] = make_float4(ev[4], ev[5], ev[6], ev[7]);
        ps += __shfl_xor(ps, 1);
        ps += __shfl_xor(ps, 2);
        ps += __shfl_xor(ps, 4);
        ps += __shfl_xor(ps, 8);
        if (g == 0) qd[r] = 1.0f / ps;
        __syncthreads();
        #pragma unroll
        for (int rr = 0; rr < 16; ++rr) {
            float invq = qd[rr];
            const float4* ap = (const float4*)&e[rr * 128 + r * 8];
            const float4* bp = (const float4*)&e[rr * 128 + g * 8];
            float4 a0 = ap[0], a1 = ap[1];
            float4 b0 = bp[0], b1 = bp[1];
            float av[8] = {a0.x*invq, a0.y*invq, a0.z*invq, a0.w*invq,
                           a1.x*invq, a1.y*invq, a1.z*invq, a1.w*invq};
            float bv[8] = {b0.x, b0.y, b0.z, b0.w, b1.x, b1.y, b1.z, b1.w};
            #pragma unroll
            for (int ii = 0; ii < 8; ++ii)
                #pragma unroll
                for (int jj = 0; jj < 8; ++jj)
                    acc[ii][jj] += av[ii] * bv[jj];
        }
        __syncthreads();
    }
    float* sp = spart + (size_t)bx * 16384;
    for (int ii = 0; ii < 8; ++ii)
        for (int jj = 0; jj < 8; ++jj)
            sp[(r * 8 + ii) * 128 + g * 8 + jj] = acc[ii][jj];
}

// ---- k2b: reduce split-N partials, apply key softmax denominator ----
__global__ __launch_bounds__(256) void k_sreduce(const float* __restrict__ spart,
                                                 const float* __restrict__ colsum,
                                                 float* __restrict__ S) {
    int i = blockIdx.x * 256 + threadIdx.x;
    int stride = gridDim.x * 256;
    for (; i < 32 * 16384; i += stride) {
        float s = 0.f;
        #pragma unroll
        for (int ns = 0; ns < 8; ++ns) s += spart[(size_t)ns * 524288 + i];
        int bh = i >> 14;
        int j = i & 127;
        int b = bh >> 3, h = bh & 7;
        S[i] = s / colsum[b * 1024 + h * 128 + j];
    }
}

// ---- k3: Wb[b][o][h*128+j] = sum_i W[o][h*128+i] * S[b,h,i,j]  (bf16 out) ----
__global__ __launch_bounds__(256) void k_fold(const float* __restrict__ W,
                                              const float* __restrict__ S,
                                              uint16_t* __restrict__ Wb) {
    int bx = blockIdx.x;                 // ot + 16*(h + 8*b)
    int ot = bx & 15, h = (bx >> 4) & 7, b = bx >> 7;
    __shared__ float Wt[128 * 132];      // transposed W tile, padded stride
    __shared__ float Sl[128 * 128];
    int t = threadIdx.x;
    int c4 = (t & 31) * 4;
    int r0 = t >> 5;
    for (int it = 0; it < 16; ++it) {
        int rr = r0 + it * 8;
        float4 wv = *(const float4*)&W[(size_t)(ot * 128 + rr) * 1024 + h * 128 + c4];
        Wt[(c4 + 0) * 132 + rr] = wv.x;
        Wt[(c4 + 1) * 132 + rr] = wv.y;
        Wt[(c4 + 2) * 132 + rr] = wv.z;
        Wt[(c4 + 3) * 132 + rr] = wv.w;
        float4 sv = *(const float4*)&S[((size_t)(b * 8 + h) * 128 + rr) * 128 + c4];
        *(float4*)&Sl[rr * 128 + c4] = sv;
    }
    __syncthreads();
    int to = (t >> 4) * 8, tj = (t & 15) * 8;
    float acc[8][8] = {};
    for (int i = 0; i < 128; ++i) {
        const float4* wp = (const float4*)&Wt[i * 132 + to];
        const float4* sp = (const float4*)&Sl[i * 128 + tj];
        float4 w0 = wp[0], w1 = wp[1];
        float4 s0 = sp[0], s1 = sp[1];
        float av[8] = {w0.x, w0.y, w0.z, w0.w, w1.x, w1.y, w1.z, w1.w};
        float bv[8] = {s0.x, s0.y, s0.z, s0.w, s1.x, s1.y, s1.z, s1.w};
        #pragma unroll
        for (int ii = 0; ii < 8; ++ii)
            #pragma unroll
            for (int jj = 0; jj < 8; ++jj)
                acc[ii][jj] += av[ii] * bv[jj];
    }
    for (int ii = 0; ii < 8; ++ii)
        for (int jj = 0; jj < 8; ++jj)
            Wb[((size_t)b * 2048 + ot * 128 + to + ii) * 1024 + h * 128 + tj + jj] =
                f2bf(acc[ii][jj]);
}

// ---- k4: Y[row][col] = sum_k A[row][k] * Bw[b][col][k]   (bf16 MFMA, m97 structure) ----
__global__ __launch_bounds__(256) void k_gemm(const uint16_t* __restrict__ A,
                                              const uint16_t* __restrict__ Bw,
                                              uint16_t* __restrict__ Y) {
    int bx = blockIdx.x;                 // ct + 16*(rt + 32*b)
    int ct = bx & 15, rt = (bx >> 4) & 31, b = bx >> 9;
    __shared__ uint16_t As[128 * 32];
    __shared__ uint16_t Bs[128 * 32];
    int t = threadIdx.x;
    int w = t >> 6, l = t & 63;
    int wr = w >> 1, wc = w & 1;
    const uint16_t* Ab = A + (size_t)(b * 4096 + rt * 128) * 1024;
    const uint16_t* Bb = Bw + (size_t)b * 2048 * 1024 + (size_t)(ct * 128) * 1024;
    f32x4_t acc[4][4];
    #pragma unroll
    for (int m = 0; m < 4; ++m)
        #pragma unroll
        for (int n = 0; n < 4; ++n)
            acc[m][n] = (f32x4_t){0.f, 0.f, 0.f, 0.f};
    int srow = t >> 2;                   // staging row 0..63
    int scol = (t & 3) * 8;              // staging col (bf16 elems)
    uint16_t* AsW = &As[w * 512];        // wave-uniform LDS base
    uint16_t* BsW = &Bs[w * 512];
    int lr = l & 15, lk = (l >> 4) * 8;
    for (int kt = 0; kt < 32; ++kt) {
        const uint16_t* Ak = Ab + (size_t)srow * 1024 + kt * 32 + scol;
        const uint16_t* Bk = Bb + (size_t)srow * 1024 + kt * 32 + scol;
        __builtin_amdgcn_global_load_lds((const AS1 void*)Ak, (AS3 void*)AsW, 16, 0, 0);
        __builtin_amdgcn_global_load_lds((const AS1 void*)(Ak + 64 * 1024), (AS3 void*)(AsW + 2048), 16, 0, 0);
        __builtin_amdgcn_global_load_lds((const AS1 void*)Bk, (AS3 void*)BsW, 16, 0, 0);
        __builtin_amdgcn_global_load_lds((const AS1 void*)(Bk + 64 * 1024), (AS3 void*)(BsW + 2048), 16, 0, 0);
        __syncthreads();
        bf16x8_t af[4], bfv[4];
        #pragma unroll
        for (int m = 0; m < 4; ++m)
            af[m] = *(const bf16x8_t*)&As[(wr * 64 + m * 16 + lr) * 32 + lk];
        #pragma unroll
        for (int n = 0; n < 4; ++n)
            bfv[n] = *(const bf16x8_t*)&Bs[(wc * 64 + n * 16 + lr) * 32 + lk];
        #pragma unroll
        for (int m = 0; m < 4; ++m)
            #pragma unroll
            for (int n = 0; n < 4; ++n)
                acc[m][n] = __builtin_amdgcn_mfma_f32_16x16x32_bf16(af[m], bfv[n], acc[m][n], 0, 0, 0);
        __syncthreads();
    }
    int lq = l >> 4;
    size_t rowb = (size_t)b * 4096 + rt * 128 + wr * 64;
    int colb = ct * 128 + wc * 64;
    #pragma unroll
    for (int m = 0; m < 4; ++m)
        #pragma unroll
        for (int n = 0; n < 4; ++n)
            #pragma unroll
            for (int q = 0; q < 4; ++q) {
                size_t row = rowb + m * 16 + lq * 4 + q;
                int col = colb + n * 16 + lr;
                Y[row * 2048 + col] = f2bf(acc[m][n][q]);
            }
}

// ---- k5: LayerNorm over 2048, f32 out ----
__global__ __launch_bounds__(256) void k_ln(const uint16_t* __restrict__ Yb,
                                            const float* __restrict__ bproj,
                                            const float* __restrict__ gamma,
                                            const float* __restrict__ beta,
                                            float* __restrict__ out) {
    int row = blockIdx.x;
    int t = threadIdx.x;
    const uint16_t* yp = Yb + (size_t)row * 2048 + t * 8;
    ushort4 u0 = ((const ushort4*)yp)[0];
    ushort4 u1 = ((const ushort4*)yp)[1];
    float4 bp0 = ((const float4*)(bproj + t * 8))[0];
    float4 bp1 = ((const float4*)(bproj + t * 8))[1];
    float v[8];
    v[0] = bf2f(u0.x) + bp0.x; v[1] = bf2f(u0.y) + bp0.y;
    v[2] = bf2f(u0.z) + bp0.z; v[3] = bf2f(u0.w) + bp0.w;
    v[4] = bf2f(u1.x) + bp1.x; v[5] = bf2f(u1.y) + bp1.y;
    v[6] = bf2f(u1.z) + bp1.z; v[7] = bf2f(u1.w) + bp1.w;
    float s = 0.f, q = 0.f;
    #pragma unroll
    for (int k = 0; k < 8; ++k) { s += v[k]; q += v[k] * v[k]; }
    #pragma unroll
    for (int m = 1; m < 64; m <<= 1) {
        s += __shfl_xor(s, m);
        q += __shfl_xor(q, m);
    }
    __shared__ float rs[4], rq[4];
    int w = t >> 6, l = t & 63;
    if (l == 0) { rs[w] = s; rq[w] = q; }
    __syncthreads();
    s = rs[0] + rs[1] + rs[2] + rs[3];
    q = rq[0] + rq[1] + rq[2] + rq[3];
    float mu = s * (1.0f / 2048.0f);
    float var = q * (1.0f / 2048.0f) - mu * mu;
    float rstd = rsqrtf(var + 1e-5f);
    float4 g0 = ((const float4*)(gamma + t * 8))[0];
    float4 g1 = ((const float4*)(gamma + t * 8))[1];
    float4 be0 = ((const float4*)(beta + t * 8))[0];
    float4 be1 = ((const float4*)(beta + t * 8))[1];
    float* op = out + (size_t)row * 2048 + t * 8;
    float4 o0, o1;
    o0.x = (v[0] - mu) * rstd * g0.x + be0.x;
    o0.y = (v[1] - mu) * rstd * g0.y + be0.y;
    o0.z = (v[2] - mu) * rstd * g0.z + be0.z;
    o0.w = (v[3] - mu) * rstd * g0.w + be0.w;
    o1.x = (v[4] - mu) * rstd * g1.x + be1.x;
    o1.y = (v[5] - mu) * rstd * g1.y + be1.y;
    o1.z = (v[6] - mu) * rstd * g1.z + be1.z;
    o1.w = (v[7] - mu) * rstd * g1.w + be1.w;
    ((float4*)op)[0] = o0;
    ((float4*)op)[1] = o1;
}

extern "C" void kernel_launch(void* const* d_in, const int* in_sizes, int n_in,
                              void* d_out, int out_size, void* d_ws, size_t ws_size,
                              hipStream_t stream) {
    const float* x1    = (const float*)d_in[0];
    const float* x2    = (const float*)d_in[1];
    const float* wproj = (const float*)d_in[2];
    const float* bproj = (const float*)d_in[3];
    const float* gamma = (const float*)d_in[4];
    const float* beta  = (const float*)d_in[5];
    float* out = (float*)d_out;

    char* ws = (char*)d_ws;
    uint16_t* x1bf   = (uint16_t*)(ws);                    // 33,554,432 B
    uint16_t* Wb     = (uint16_t*)(ws + 33554432);         // 16,777,216 B
    uint16_t* Y      = (uint16_t*)(ws + 50331648);         // 67,108,864 B
    float*    colsum = (float*)   (ws + 117440512);        //     16,384 B
    float*    spart  = (float*)   (ws + 117456896);        // 16,777,216 B
    float*    S      = (float*)   (ws + 134234112);        //  2,097,152 B
    // total 136,331,264 B

    hipMemsetAsync(colsum, 0, 4096 * sizeof(float), stream);
    k_convert<<<2048, 256, 0, stream>>>(x1, x1bf, 16384 * 1024 / 4);
    k_colsum<<<256, 256, 0, stream>>>(x2, colsum);
    k_spart<<<256, 256, 0, stream>>>(x2, spart);
    k_sreduce<<<512, 256, 0, stream>>>(spart, colsum, S);
    k_fold<<<512, 256, 0, stream>>>(wproj, S, Wb);
    k_gemm<<<2048, 256, 0, stream>>>(x1bf, Wb, Y);
    k_ln<<<16384, 256, 0, stream>>>(Y, bproj, gamma, beta, out);
}

// Round 2
// 375.292 us; speedup vs baseline: 1.3065x; 1.3065x over previous
//
#include <hip/hip_runtime.h>
#include <stdint.h>

#define AS1 __attribute__((address_space(1)))
#define AS3 __attribute__((address_space(3)))

using bf16x8_t = __attribute__((ext_vector_type(8))) __bf16;
using f32x4_t  = __attribute__((ext_vector_type(4))) float;

__device__ __forceinline__ uint16_t f2bf(float f) {
    union { float f; uint32_t u; } v; v.f = f;
    return (uint16_t)((v.u + 0x7fffu + ((v.u >> 16) & 1u)) >> 16);
}
__device__ __forceinline__ float bf2f(uint16_t h) {
    union { uint32_t u; float f; } v; v.u = ((uint32_t)h) << 16;
    return v.f;
}

// ---- k0: f32 -> bf16 (used for x1 and w_proj) ----
__global__ __launch_bounds__(256) void k_convert(const float* __restrict__ x,
                                                 uint16_t* __restrict__ o, int n4) {
    int i = blockIdx.x * 256 + threadIdx.x;
    int stride = gridDim.x * 256;
    for (; i < n4; i += stride) {
        float4 v = ((const float4*)x)[i];
        ushort4 u;
        u.x = f2bf(v.x); u.y = f2bf(v.y); u.z = f2bf(v.z); u.w = f2bf(v.w);
        ((ushort4*)o)[i] = u;
    }
}

// ---- k_sF: per (b,h,ns): F[n,c] = exp(x2)·rsqrt(qden[n]) (bf16 in LDS),
//      S_raw partial = F^T F via MFMA; fused colsum (key-softmax denom) atomics ----
__global__ __launch_bounds__(256) void k_sF(const float* __restrict__ x2,
                                            float* __restrict__ spart,
                                            float* __restrict__ colsum) {
    int bx = blockIdx.x;
    int bh = bx & 31, ns = bx >> 5;       // ns 0..15 (256-row chunk)
    int b = bh >> 3, h = bh & 7;
    __shared__ uint32_t F[128 * 64];      // F_dw[c][64 np], 16B-granule XOR swizzled
    __shared__ float cs[128];
    int t = threadIdx.x;
    int g = t & 15, rp = t >> 4;          // g: 8-ch group, rp: row-pair slot 0..15
    int w = t >> 6, l = t & 63;
    int c15 = l & 15, kg = l >> 4;
    if (t < 128) cs[t] = 0.f;
    f32x4_t acc[8][2];
    #pragma unroll
    for (int it = 0; it < 8; ++it) {
        acc[it][0] = (f32x4_t){0.f, 0.f, 0.f, 0.f};
        acc[it][1] = (f32x4_t){0.f, 0.f, 0.f, 0.f};
    }
    float csl[8] = {0.f, 0.f, 0.f, 0.f, 0.f, 0.f, 0.f, 0.f};
    const float* xb = x2 + ((size_t)(b * 4096 + ns * 256)) * 1024 + h * 128 + g * 8;
    int swz = g & 7;
    for (int half = 0; half < 2; ++half) {
        if (half) __syncthreads();
        // Phase A: exp + row-softmax denom + transposed bf16 write into F
        #pragma unroll
        for (int it = 0; it < 4; ++it) {
            int np = rp + it * 16;        // 0..63 within half
            int n0 = half * 128 + np * 2;
            const float* p0 = xb + (size_t)n0 * 1024;
            float4 a0 = ((const float4*)p0)[0];
            float4 a1 = ((const float4*)p0)[1];
            float4 b0 = ((const float4*)(p0 + 1024))[0];
            float4 b1 = ((const float4*)(p0 + 1024))[1];
            float e0[8], e1[8];
            e0[0] = __expf(a0.x); e0[1] = __expf(a0.y); e0[2] = __expf(a0.z); e0[3] = __expf(a0.w);
            e0[4] = __expf(a1.x); e0[5] = __expf(a1.y); e0[6] = __expf(a1.z); e0[7] = __expf(a1.w);
            e1[0] = __expf(b0.x); e1[1] = __expf(b0.y); e1[2] = __expf(b0.z); e1[3] = __expf(b0.w);
            e1[4] = __expf(b1.x); e1[5] = __expf(b1.y); e1[6] = __expf(b1.z); e1[7] = __expf(b1.w);
            float s0 = ((e0[0]+e0[1])+(e0[2]+e0[3])) + ((e0[4]+e0[5])+(e0[6]+e0[7]));
            float s1 = ((e1[0]+e1[1])+(e1[2]+e1[3])) + ((e1[4]+e1[5])+(e1[6]+e1[7]));
            #pragma unroll
            for (int m2 = 1; m2 < 16; m2 <<= 1) {
                s0 += __shfl_xor(s0, m2);
                s1 += __shfl_xor(s1, m2);
            }
            float r0 = rsqrtf(s0), r1 = rsqrtf(s1);
            int blk = it * 4 + (rp >> 2);
            uint32_t* Fw = &F[g * 512 + ((blk ^ swz) << 2) + (rp & 3)];
            #pragma unroll
            for (int m = 0; m < 8; ++m) {
                Fw[m * 64] = (uint32_t)f2bf(e0[m] * r0) | ((uint32_t)f2bf(e1[m] * r1) << 16);
                csl[m] += e0[m] + e1[m];
            }
        }
        __syncthreads();
        // Phase B: S_raw += F^T F over this half's K=128
        #pragma unroll
        for (int kk2 = 0; kk2 < 4; ++kk2) {
            bf16x8_t Bf[2];
            #pragma unroll
            for (int jt = 0; jt < 2; ++jt) {
                int c = w * 32 + jt * 16 + c15;
                Bf[jt] = *(const bf16x8_t*)&F[c * 64 + (((kk2 * 4 + kg) ^ ((c >> 3) & 7)) << 2)];
            }
            #pragma unroll
            for (int it = 0; it < 8; ++it) {
                int c = it * 16 + c15;
                bf16x8_t Af = *(const bf16x8_t*)&F[c * 64 + (((kk2 * 4 + kg) ^ ((c >> 3) & 7)) << 2)];
                acc[it][0] = __builtin_amdgcn_mfma_f32_16x16x32_bf16(Af, Bf[0], acc[it][0], 0, 0, 0);
                acc[it][1] = __builtin_amdgcn_mfma_f32_16x16x32_bf16(Af, Bf[1], acc[it][1], 0, 0, 0);
            }
        }
    }
    // colsum: reduce csl over rp within wave, combine waves via LDS atomics
    #pragma unroll
    for (int m = 0; m < 8; ++m) {
        csl[m] += __shfl_xor(csl[m], 16);
        csl[m] += __shfl_xor(csl[m], 32);
    }
    if ((t & 48) == 0) {
        #pragma unroll
        for (int m = 0; m < 8; ++m) atomicAdd(&cs[g * 8 + m], csl[m]);
    }
    __syncthreads();
    if (t < 128) atomicAdd(&colsum[b * 1024 + h * 128 + t], cs[t]);
    // write S_raw partial
    float* sp = spart + ((size_t)(ns * 32 + bh)) * 16384;
    #pragma unroll
    for (int it = 0; it < 8; ++it)
        #pragma unroll
        for (int jt = 0; jt < 2; ++jt)
            #pragma unroll
            for (int q = 0; q < 4; ++q)
                sp[(it * 16 + kg * 4 + q) * 128 + w * 32 + jt * 16 + c15] = acc[it][jt][q];
}

// ---- k_sred: sum 16 K-partials, scale by 1/colsum[j], write SbfT[bh][j][i] bf16 ----
__global__ __launch_bounds__(256) void k_sred(const float* __restrict__ spart,
                                              const float* __restrict__ colsum,
                                              uint16_t* __restrict__ SbfT) {
    int bx = blockIdx.x;
    int bh = bx >> 3, ic = bx & 7;        // i-chunk of 16 rows
    int b = bh >> 3, h = bh & 7;
    __shared__ float T[128 * 17];         // T[j][i_local], stride 17
    int t = threadIdx.x;
    int il = t >> 4, g = t & 15;
    int i = ic * 16 + il;
    const float* sp = spart + (size_t)bh * 16384 + (size_t)i * 128 + g * 8;
    float v[8] = {0.f, 0.f, 0.f, 0.f, 0.f, 0.f, 0.f, 0.f};
    #pragma unroll
    for (int ns = 0; ns < 16; ++ns) {
        float4 u0 = ((const float4*)(sp + (size_t)ns * 524288))[0];
        float4 u1 = ((const float4*)(sp + (size_t)ns * 524288))[1];
        v[0] += u0.x; v[1] += u0.y; v[2] += u0.z; v[3] += u0.w;
        v[4] += u1.x; v[5] += u1.y; v[6] += u1.z; v[7] += u1.w;
    }
    const float* cp = colsum + b * 1024 + h * 128 + g * 8;
    float4 c0 = ((const float4*)cp)[0];
    float4 c1 = ((const float4*)cp)[1];
    T[(g * 8 + 0) * 17 + il] = v[0] / c0.x;
    T[(g * 8 + 1) * 17 + il] = v[1] / c0.y;
    T[(g * 8 + 2) * 17 + il] = v[2] / c0.z;
    T[(g * 8 + 3) * 17 + il] = v[3] / c0.w;
    T[(g * 8 + 4) * 17 + il] = v[4] / c1.x;
    T[(g * 8 + 5) * 17 + il] = v[5] / c1.y;
    T[(g * 8 + 6) * 17 + il] = v[6] / c1.z;
    T[(g * 8 + 7) * 17 + il] = v[7] / c1.w;
    __syncthreads();
    int j = t >> 1, ih = t & 1;
    const float* tp = &T[j * 17 + ih * 8];
    uint4 o;
    o.x = (uint32_t)f2bf(tp[0]) | ((uint32_t)f2bf(tp[1]) << 16);
    o.y = (uint32_t)f2bf(tp[2]) | ((uint32_t)f2bf(tp[3]) << 16);
    o.z = (uint32_t)f2bf(tp[4]) | ((uint32_t)f2bf(tp[5]) << 16);
    o.w = (uint32_t)f2bf(tp[6]) | ((uint32_t)f2bf(tp[7]) << 16);
    *(uint4*)(SbfT + (size_t)bh * 16384 + (size_t)j * 128 + ic * 16 + ih * 8) = o;
}

// ---- k_fold: Wb[b][o][h*128+j] = sum_i Wbf[o][h*128+i] * S[b,h][i][j]  (MFMA, LDS-free) ----
__global__ __launch_bounds__(256) void k_fold(const uint16_t* __restrict__ Wbf,
                                              const uint16_t* __restrict__ SbfT,
                                              uint16_t* __restrict__ Wb) {
    int bx = blockIdx.x;
    int ot = bx & 15, h = (bx >> 4) & 7, b = bx >> 7;
    int bh = b * 8 + h;
    int t = threadIdx.x;
    int w = t >> 6, l = t & 63;
    int c15 = l & 15, kg = l >> 4;
    f32x4_t acc[2][8];
    #pragma unroll
    for (int it2 = 0; it2 < 2; ++it2)
        #pragma unroll
        for (int jt = 0; jt < 8; ++jt)
            acc[it2][jt] = (f32x4_t){0.f, 0.f, 0.f, 0.f};
    const uint16_t* Abase = Wbf + (size_t)(ot * 128 + w * 32 + c15) * 1024 + h * 128 + kg * 8;
    const uint16_t* Bbase = SbfT + (size_t)bh * 16384 + (size_t)c15 * 128 + kg * 8;
    #pragma unroll
    for (int kk2 = 0; kk2 < 4; ++kk2) {
        bf16x8_t Af0 = *(const bf16x8_t*)(Abase + kk2 * 32);
        bf16x8_t Af1 = *(const bf16x8_t*)(Abase + 16 * 1024 + kk2 * 32);
        bf16x8_t Bf[8];
        #pragma unroll
        for (int jt = 0; jt < 8; ++jt)
            Bf[jt] = *(const bf16x8_t*)(Bbase + (size_t)jt * 16 * 128 + kk2 * 32);
        #pragma unroll
        for (int jt = 0; jt < 8; ++jt) {
            acc[0][jt] = __builtin_amdgcn_mfma_f32_16x16x32_bf16(Af0, Bf[jt], acc[0][jt], 0, 0, 0);
            acc[1][jt] = __builtin_amdgcn_mfma_f32_16x16x32_bf16(Af1, Bf[jt], acc[1][jt], 0, 0, 0);
        }
    }
    #pragma unroll
    for (int it2 = 0; it2 < 2; ++it2)
        #pragma unroll
        for (int jt = 0; jt < 8; ++jt)
            #pragma unroll
            for (int q = 0; q < 4; ++q) {
                int o = ot * 128 + w * 32 + it2 * 16 + kg * 4 + q;
                int j = jt * 16 + c15;
                Wb[((size_t)b * 2048 + o) * 1024 + h * 128 + j] = f2bf(acc[it2][jt][q]);
            }
}

// ---- k_gemm: Y[row][col] = sum_k A[row][k] * Bw[b][col][k]  (bf16 MFMA, m97 structure) ----
__global__ __launch_bounds__(256) void k_gemm(const uint16_t* __restrict__ A,
                                              const uint16_t* __restrict__ Bw,
                                              uint16_t* __restrict__ Y) {
    int bx = blockIdx.x;
    bx = ((bx & 7) << 8) | (bx >> 3);     // XCD-aware swizzle (2048 % 8 == 0)
    int ct = bx & 15, rt = (bx >> 4) & 31, b = bx >> 9;
    __shared__ uint16_t As[128 * 32];
    __shared__ uint16_t Bs[128 * 32];
    int t = threadIdx.x;
    int w = t >> 6, l = t & 63;
    int wr = w >> 1, wc = w & 1;
    const uint16_t* Ab = A + (size_t)(b * 4096 + rt * 128) * 1024;
    const uint16_t* Bb = Bw + (size_t)b * 2048 * 1024 + (size_t)(ct * 128) * 1024;
    f32x4_t acc[4][4];
    #pragma unroll
    for (int m = 0; m < 4; ++m)
        #pragma unroll
        for (int n = 0; n < 4; ++n)
            acc[m][n] = (f32x4_t){0.f, 0.f, 0.f, 0.f};
    int srow = t >> 2;
    int scol = (t & 3) * 8;
    uint16_t* AsW = &As[w * 512];
    uint16_t* BsW = &Bs[w * 512];
    int lr = l & 15, lk = (l >> 4) * 8;
    for (int kt = 0; kt < 32; ++kt) {
        const uint16_t* Ak = Ab + (size_t)srow * 1024 + kt * 32 + scol;
        const uint16_t* Bk = Bb + (size_t)srow * 1024 + kt * 32 + scol;
        __builtin_amdgcn_global_load_lds((const AS1 void*)Ak, (AS3 void*)AsW, 16, 0, 0);
        __builtin_amdgcn_global_load_lds((const AS1 void*)(Ak + 64 * 1024), (AS3 void*)(AsW + 2048), 16, 0, 0);
        __builtin_amdgcn_global_load_lds((const AS1 void*)Bk, (AS3 void*)BsW, 16, 0, 0);
        __builtin_amdgcn_global_load_lds((const AS1 void*)(Bk + 64 * 1024), (AS3 void*)(BsW + 2048), 16, 0, 0);
        __syncthreads();
        bf16x8_t af[4], bfv[4];
        #pragma unroll
        for (int m = 0; m < 4; ++m)
            af[m] = *(const bf16x8_t*)&As[(wr * 64 + m * 16 + lr) * 32 + lk];
        #pragma unroll
        for (int n = 0; n < 4; ++n)
            bfv[n] = *(const bf16x8_t*)&Bs[(wc * 64 + n * 16 + lr) * 32 + lk];
        #pragma unroll
        for (int m = 0; m < 4; ++m)
            #pragma unroll
            for (int n = 0; n < 4; ++n)
                acc[m][n] = __builtin_amdgcn_mfma_f32_16x16x32_bf16(af[m], bfv[n], acc[m][n], 0, 0, 0);
        __syncthreads();
    }
    int lq = l >> 4;
    size_t rowb = (size_t)b * 4096 + rt * 128 + wr * 64;
    int colb = ct * 128 + wc * 64;
    #pragma unroll
    for (int m = 0; m < 4; ++m)
        #pragma unroll
        for (int n = 0; n < 4; ++n)
            #pragma unroll
            for (int q = 0; q < 4; ++q) {
                size_t row = rowb + m * 16 + lq * 4 + q;
                int col = colb + n * 16 + lr;
                Y[row * 2048 + col] = f2bf(acc[m][n][q]);
            }
}

// ---- k_ln: LayerNorm over 2048, f32 out ----
__global__ __launch_bounds__(256) void k_ln(const uint16_t* __restrict__ Yb,
                                            const float* __restrict__ bproj,
                                            const float* __restrict__ gamma,
                                            const float* __restrict__ beta,
                                            float* __restrict__ out) {
    int row = blockIdx.x;
    int t = threadIdx.x;
    const uint16_t* yp = Yb + (size_t)row * 2048 + t * 8;
    ushort4 u0 = ((const ushort4*)yp)[0];
    ushort4 u1 = ((const ushort4*)yp)[1];
    float4 bp0 = ((const float4*)(bproj + t * 8))[0];
    float4 bp1 = ((const float4*)(bproj + t * 8))[1];
    float v[8];
    v[0] = bf2f(u0.x) + bp0.x; v[1] = bf2f(u0.y) + bp0.y;
    v[2] = bf2f(u0.z) + bp0.z; v[3] = bf2f(u0.w) + bp0.w;
    v[4] = bf2f(u1.x) + bp1.x; v[5] = bf2f(u1.y) + bp1.y;
    v[6] = bf2f(u1.z) + bp1.z; v[7] = bf2f(u1.w) + bp1.w;
    float s = 0.f, q = 0.f;
    #pragma unroll
    for (int k = 0; k < 8; ++k) { s += v[k]; q += v[k] * v[k]; }
    #pragma unroll
    for (int m = 1; m < 64; m <<= 1) {
        s += __shfl_xor(s, m);
        q += __shfl_xor(q, m);
    }
    __shared__ float rs[4], rq[4];
    int w = t >> 6, l = t & 63;
    if (l == 0) { rs[w] = s; rq[w] = q; }
    __syncthreads();
    s = rs[0] + rs[1] + rs[2] + rs[3];
    q = rq[0] + rq[1] + rq[2] + rq[3];
    float mu = s * (1.0f / 2048.0f);
    float var = q * (1.0f / 2048.0f) - mu * mu;
    float rstd = rsqrtf(var + 1e-5f);
    float4 g0 = ((const float4*)(gamma + t * 8))[0];
    float4 g1 = ((const float4*)(gamma + t * 8))[1];
    float4 be0 = ((const float4*)(beta + t * 8))[0];
    float4 be1 = ((const float4*)(beta + t * 8))[1];
    float* op = out + (size_t)row * 2048 + t * 8;
    float4 o0, o1;
    o0.x = (v[0] - mu) * rstd * g0.x + be0.x;
    o0.y = (v[1] - mu) * rstd * g0.y + be0.y;
    o0.z = (v[2] - mu) * rstd * g0.z + be0.z;
    o0.w = (v[3] - mu) * rstd * g0.w + be0.w;
    o1.x = (v[4] - mu) * rstd * g1.x + be1.x;
    o1.y = (v[5] - mu) * rstd * g1.y + be1.y;
    o1.z = (v[6] - mu) * rstd * g1.z + be1.z;
    o1.w = (v[7] - mu) * rstd * g1.w + be1.w;
    ((float4*)op)[0] = o0;
    ((float4*)op)[1] = o1;
}

extern "C" void kernel_launch(void* const* d_in, const int* in_sizes, int n_in,
                              void* d_out, int out_size, void* d_ws, size_t ws_size,
                              hipStream_t stream) {
    const float* x1    = (const float*)d_in[0];
    const float* x2    = (const float*)d_in[1];
    const float* wproj = (const float*)d_in[2];
    const float* bproj = (const float*)d_in[3];
    const float* gamma = (const float*)d_in[4];
    const float* beta  = (const float*)d_in[5];
    float* out = (float*)d_out;

    char* ws = (char*)d_ws;
    uint16_t* x1bf   = (uint16_t*)(ws);                    // 33,554,432 B
    uint16_t* Wbf    = (uint16_t*)(ws + 33554432);         //  4,194,304 B
    uint16_t* Wb     = (uint16_t*)(ws + 37748736);         // 16,777,216 B
    uint16_t* Y      = (uint16_t*)(ws + 54525952);         // 67,108,864 B
    float*    spart  = (float*)   (ws + 54525952);         // aliases Y (33.5 MB used, freed before k_gemm)
    uint16_t* SbfT   = (uint16_t*)(ws + 121634816);        //  1,048,576 B
    float*    colsum = (float*)   (ws + 122683392);        //     16,384 B
    // total 122,699,776 B

    hipMemsetAsync(colsum, 0, 4096 * sizeof(float), stream);
    k_convert<<<2048, 256, 0, stream>>>(x1, x1bf, 4194304);
    k_convert<<<512, 256, 0, stream>>>(wproj, Wbf, 524288);
    k_sF<<<512, 256, 0, stream>>>(x2, spart, colsum);
    k_sred<<<256, 256, 0, stream>>>(spart, colsum, SbfT);
    k_fold<<<512, 256, 0, stream>>>(Wbf, SbfT, Wb);
    k_gemm<<<2048, 256, 0, stream>>>(x1bf, Wb, Y);
    k_ln<<<16384, 256, 0, stream>>>(Y, bproj, gamma, beta, out);
}